// Round 3
// baseline (274.821 us; speedup 1.0000x reference)
//
#include <hip/hip_runtime.h>
#include <hip/hip_cooperative_groups.h>
#include <math.h>

namespace cg = cooperative_groups;

#define N_NODES  100000
#define D_FEAT   128
#define N_EDGES  640000
#define NBLOCKS  1024
#define NTHREADS 256

// ---------------------------------------------------------------------------
// Fused cooperative kernel.
// Phase 0: prefetch per-thread edge indices into registers (overlaps phase 1).
// Phase 1: per-node dot products a[n]=feat[n]·W[:128], c[n]=feat[n]·W[128:].
//          32-lane groups, float4/lane (512 B row per group), 2 nodes/iter.
// Fence + grid.sync + fence: cross-XCD visibility of a/c (Guideline 16).
// Phase 2: out[e] = sigmoid(a[src]+c[dst]+b), 4 edges/thread, float4 store.
// ---------------------------------------------------------------------------
__launch_bounds__(NTHREADS, 4)
__global__ void fused_kernel(const float* __restrict__ feat,
                             const int* __restrict__ ei,
                             const float* __restrict__ W,
                             const float* __restrict__ bias,
                             float* __restrict__ a,
                             float* __restrict__ c,
                             float* __restrict__ out)
{
    const int tid = blockIdx.x * NTHREADS + threadIdx.x;

    // ---- Phase 0: edge-index prefetch (rides under phase 1's HBM stream) ----
    const int e0 = tid * 4;
    const bool has_edges = (e0 < N_EDGES);   // N_EDGES % 4 == 0
    int4 se = make_int4(0, 0, 0, 0);
    int4 de = make_int4(0, 0, 0, 0);
    if (has_edges) {
        se = *reinterpret_cast<const int4*>(ei + e0);
        de = *reinterpret_cast<const int4*>(ei + N_EDGES + e0);
    }

    // ---- Phase 1: node dots ----
    const int lane32 = threadIdx.x & 31;
    const int grp    = tid >> 5;
    const int ngrp   = (NBLOCKS * NTHREADS) >> 5;   // 8192 groups

    const float4 w0 = *reinterpret_cast<const float4*>(W + lane32 * 4);
    const float4 w1 = *reinterpret_cast<const float4*>(W + D_FEAT + lane32 * 4);

    // N_NODES is even, stride ngrp*2: n0 even, n1=n0+1 always valid
    for (int n0 = grp * 2; n0 < N_NODES; n0 += ngrp * 2) {
        const int n1 = n0 + 1;

        const float4 f0 = *reinterpret_cast<const float4*>(feat + (size_t)n0 * D_FEAT + lane32 * 4);
        const float4 f1 = *reinterpret_cast<const float4*>(feat + (size_t)n1 * D_FEAT + lane32 * 4);

        float pa0 = f0.x * w0.x + f0.y * w0.y + f0.z * w0.z + f0.w * w0.w;
        float pc0 = f0.x * w1.x + f0.y * w1.y + f0.z * w1.z + f0.w * w1.w;
        float pa1 = f1.x * w0.x + f1.y * w0.y + f1.z * w0.z + f1.w * w0.w;
        float pc1 = f1.x * w1.x + f1.y * w1.y + f1.z * w1.z + f1.w * w1.w;

        #pragma unroll
        for (int off = 16; off > 0; off >>= 1) {
            pa0 += __shfl_down(pa0, off, 32);
            pc0 += __shfl_down(pc0, off, 32);
            pa1 += __shfl_down(pa1, off, 32);
            pc1 += __shfl_down(pc1, off, 32);
        }
        if (lane32 == 0) {
            a[n0] = pa0;
            c[n0] = pc0;
            a[n1] = pa1;
            c[n1] = pc1;
        }
    }

    // ---- Cross-XCD hand-off: release (wb L2) -> barrier -> acquire (inv L2) ----
    __threadfence();        // write back dirty a/c lines to the coherence point
    cg::this_grid().sync();
    __threadfence();        // invalidate stale-clean lines (incl. 0xAA poison)

    // ---- Phase 2: gather + sigmoid ----
    if (has_edges) {
        const float bb = bias[0];
        float4 o;
        o.x = 1.0f / (1.0f + __expf(-(a[se.x] + c[de.x] + bb)));
        o.y = 1.0f / (1.0f + __expf(-(a[se.y] + c[de.y] + bb)));
        o.z = 1.0f / (1.0f + __expf(-(a[se.z] + c[de.z] + bb)));
        o.w = 1.0f / (1.0f + __expf(-(a[se.w] + c[de.w] + bb)));
        *reinterpret_cast<float4*>(out + e0) = o;
    }
}

// ---------------------------------------------------------------------------
// Fallback two-kernel path (proven correct in R1/R2), used only if the
// cooperative launch is rejected at runtime.
// ---------------------------------------------------------------------------
__global__ void node_dots_kernel(const float* __restrict__ feat,
                                 const float* __restrict__ W,
                                 float* __restrict__ a,
                                 float* __restrict__ c)
{
    const int lane32 = threadIdx.x & 31;
    const int grp    = (blockIdx.x * blockDim.x + threadIdx.x) >> 5;
    const int ngrp   = (gridDim.x * blockDim.x) >> 5;

    const float4 w0 = *reinterpret_cast<const float4*>(W + lane32 * 4);
    const float4 w1 = *reinterpret_cast<const float4*>(W + D_FEAT + lane32 * 4);

    for (int n0 = grp * 2; n0 < N_NODES; n0 += ngrp * 2) {
        const int n1 = n0 + 1;
        const float4 f0 = *reinterpret_cast<const float4*>(feat + (size_t)n0 * D_FEAT + lane32 * 4);
        const float4 f1 = *reinterpret_cast<const float4*>(feat + (size_t)n1 * D_FEAT + lane32 * 4);

        float pa0 = f0.x * w0.x + f0.y * w0.y + f0.z * w0.z + f0.w * w0.w;
        float pc0 = f0.x * w1.x + f0.y * w1.y + f0.z * w1.z + f0.w * w1.w;
        float pa1 = f1.x * w0.x + f1.y * w0.y + f1.z * w0.z + f1.w * w0.w;
        float pc1 = f1.x * w1.x + f1.y * w1.y + f1.z * w1.z + f1.w * w1.w;

        #pragma unroll
        for (int off = 16; off > 0; off >>= 1) {
            pa0 += __shfl_down(pa0, off, 32);
            pc0 += __shfl_down(pc0, off, 32);
            pa1 += __shfl_down(pa1, off, 32);
            pc1 += __shfl_down(pc1, off, 32);
        }
        if (lane32 == 0) {
            a[n0] = pa0;
            c[n0] = pc0;
            a[n1] = pa1;
            c[n1] = pc1;
        }
    }
}

__global__ void edge_kernel(const int* __restrict__ ei,
                            const float* __restrict__ a,
                            const float* __restrict__ c,
                            const float* __restrict__ b,
                            float* __restrict__ out)
{
    const int t = blockIdx.x * blockDim.x + threadIdx.x;
    const int e0 = t * 4;
    if (e0 >= N_EDGES) return;

    const float bb = b[0];
    const int4 s = *reinterpret_cast<const int4*>(ei + e0);
    const int4 d = *reinterpret_cast<const int4*>(ei + N_EDGES + e0);

    float4 o;
    o.x = 1.0f / (1.0f + __expf(-(a[s.x] + c[d.x] + bb)));
    o.y = 1.0f / (1.0f + __expf(-(a[s.y] + c[d.y] + bb)));
    o.z = 1.0f / (1.0f + __expf(-(a[s.z] + c[d.z] + bb)));
    o.w = 1.0f / (1.0f + __expf(-(a[s.w] + c[d.w] + bb)));

    *reinterpret_cast<float4*>(out + e0) = o;
}

extern "C" void kernel_launch(void* const* d_in, const int* in_sizes, int n_in,
                              void* d_out, int out_size, void* d_ws, size_t ws_size,
                              hipStream_t stream)
{
    const float* feat = (const float*)d_in[0];
    const int*   ei   = (const int*)d_in[1];   // harness converts int64 -> int32
    const float* W    = (const float*)d_in[2];
    const float* b    = (const float*)d_in[3];
    float*       out  = (float*)d_out;

    float* a = (float*)d_ws;
    float* c = a + N_NODES;

    void* args[] = {(void*)&feat, (void*)&ei, (void*)&W, (void*)&b,
                    (void*)&a, (void*)&c, (void*)&out};

    hipError_t err = hipLaunchCooperativeKernel((const void*)fused_kernel,
                                                dim3(NBLOCKS), dim3(NTHREADS),
                                                args, 0, stream);
    if (err != hipSuccess) {
        // Fallback: proven two-kernel path
        node_dots_kernel<<<1024, 256, 0, stream>>>(feat, W, a, c);
        const int nthreads = N_EDGES / 4;
        const int nblk2 = (nthreads + 255) / 256;
        edge_kernel<<<nblk2, 256, 0, stream>>>(ei, a, c, b, out);
    }
}

// Round 4
// 22.995 us; speedup vs baseline: 11.9515x; 11.9515x over previous
//
#include <hip/hip_runtime.h>
#include <math.h>

#define N_NODES 100000
#define D_FEAT  128
#define N_EDGES 640000

#define ROWS_PER_CHUNK 16
#define N_CHUNKS (N_NODES / ROWS_PER_CHUNK)   // 6250 exactly
#define K1_WPB   4                            // waves per block
#define K1_BLOCK (K1_WPB * 64)
#define K1_GRID  782                          // ~2 chunks per wave

// ---------------------------------------------------------------------------
// Kernel 1: a[n] = feat[n]·W[:128], c[n] = feat[n]·W[128:] via LDS transpose.
// Per wave-iteration: stage 16 rows (8 KB) coalesced into a private LDS slab,
// then each lane reduces a quarter-row from LDS (W fragment in registers).
// Only 4 shuffles per 16 rows. No __syncthreads (wave-private slab; per-wave
// DS ops are in-order).
// ---------------------------------------------------------------------------
__global__ __launch_bounds__(K1_BLOCK) void node_dots_kernel(
    const float* __restrict__ feat, const float* __restrict__ W,
    float* __restrict__ a, float* __restrict__ c)
{
    // pad row stride to 33 float4s: read/write bank-quads spread evenly
    __shared__ float4 lds[K1_WPB][ROWS_PER_CHUNK][33];

    const int wave  = threadIdx.x >> 6;
    const int lane  = threadIdx.x & 63;
    const int gwave = blockIdx.x * K1_WPB + wave;
    const int nwav  = gridDim.x * K1_WPB;

    const int r = lane & 15;   // row within chunk
    const int q = lane >> 4;   // quarter of the row (32 floats)

    // W fragments for this lane's quarter: 8 float4 each for W0 / W1
    float4 w0[8], w1[8];
    #pragma unroll
    for (int j = 0; j < 8; ++j) {
        w0[j] = *reinterpret_cast<const float4*>(W + q * 32 + j * 4);
        w1[j] = *reinterpret_cast<const float4*>(W + D_FEAT + q * 32 + j * 4);
    }

    for (int ch = gwave; ch < N_CHUNKS; ch += nwav) {
        const size_t base = (size_t)ch * ROWS_PER_CHUNK * D_FEAT;

        // ---- stage 16 rows, fully coalesced, all 8 loads in flight ----
        float4 st[8];
        #pragma unroll
        for (int k = 0; k < 8; ++k) {
            const int g = k * 64 + lane;              // float4-chunk index 0..511
            st[k] = *reinterpret_cast<const float4*>(feat + base + (size_t)g * 4);
        }
        #pragma unroll
        for (int k = 0; k < 8; ++k) {
            const int g = k * 64 + lane;
            lds[wave][g >> 5][g & 31] = st[k];
        }

        // ---- each lane reduces its quarter-row from LDS ----
        float pa = 0.f, pc = 0.f;
        #pragma unroll
        for (int j = 0; j < 8; ++j) {
            const float4 f = lds[wave][r][q * 8 + j];
            pa += f.x * w0[j].x + f.y * w0[j].y + f.z * w0[j].z + f.w * w0[j].w;
            pc += f.x * w1[j].x + f.y * w1[j].y + f.z * w1[j].z + f.w * w1[j].w;
        }

        // combine the 4 quarters: lanes {r, r+16, r+32, r+48}
        pa += __shfl_down(pa, 16, 64);
        pc += __shfl_down(pc, 16, 64);
        pa += __shfl_down(pa, 32, 64);
        pc += __shfl_down(pc, 32, 64);

        if (lane < 16) {
            const int n = ch * ROWS_PER_CHUNK + r;
            a[n] = pa;
            c[n] = pc;
        }
    }
}

// ---------------------------------------------------------------------------
// Kernel 2: per-edge gather of precomputed dots + sigmoid, 4 edges/thread.
// Gather tables (800 KB) are L2/L3-resident.
// ---------------------------------------------------------------------------
__global__ void edge_kernel(const int* __restrict__ ei,
                            const float* __restrict__ a,
                            const float* __restrict__ c,
                            const float* __restrict__ b,
                            float* __restrict__ out)
{
    const int t = blockIdx.x * blockDim.x + threadIdx.x;
    const int e0 = t * 4;
    if (e0 >= N_EDGES) return;

    const float bb = b[0];
    const int4 s = *reinterpret_cast<const int4*>(ei + e0);
    const int4 d = *reinterpret_cast<const int4*>(ei + N_EDGES + e0);

    float4 o;
    o.x = 1.0f / (1.0f + __expf(-(a[s.x] + c[d.x] + bb)));
    o.y = 1.0f / (1.0f + __expf(-(a[s.y] + c[d.y] + bb)));
    o.z = 1.0f / (1.0f + __expf(-(a[s.z] + c[d.z] + bb)));
    o.w = 1.0f / (1.0f + __expf(-(a[s.w] + c[d.w] + bb)));

    *reinterpret_cast<float4*>(out + e0) = o;
}

extern "C" void kernel_launch(void* const* d_in, const int* in_sizes, int n_in,
                              void* d_out, int out_size, void* d_ws, size_t ws_size,
                              hipStream_t stream)
{
    const float* feat = (const float*)d_in[0];
    const int*   ei   = (const int*)d_in[1];   // harness converts int64 -> int32
    const float* W    = (const float*)d_in[2];
    const float* b    = (const float*)d_in[3];
    float*       out  = (float*)d_out;

    float* a = (float*)d_ws;
    float* c = a + N_NODES;

    node_dots_kernel<<<K1_GRID, K1_BLOCK, 0, stream>>>(feat, W, a, c);

    const int nthreads = N_EDGES / 4;            // 160000
    const int nblk2 = (nthreads + 255) / 256;    // 625
    edge_kernel<<<nblk2, 256, 0, stream>>>(ei, a, c, b, out);
}

// Round 6
// 22.686 us; speedup vs baseline: 12.1144x; 1.0136x over previous
//
#include <hip/hip_runtime.h>
#include <math.h>

#define N_NODES 100000
#define D_FEAT  128
#define N_EDGES 640000

// native vector type for nontemporal builtin (HIP_vector_type is rejected)
typedef float nfloat4 __attribute__((ext_vector_type(4)));

// ---------------------------------------------------------------------------
// Kernel 1: a[n] = feat[n]·W[:128] + bias, c[n] = feat[n]·W[128:].
// 32-lane groups, float4/lane (512 B per row per group), 4 nodes in flight
// per iteration. Grid-stride. Bias folded into a[] so kernel 2 needs no b.
// ---------------------------------------------------------------------------
__global__ __launch_bounds__(256) void node_dots_kernel(
    const float* __restrict__ feat, const float* __restrict__ W,
    const float* __restrict__ bias,
    float* __restrict__ a, float* __restrict__ c)
{
    const int lane32 = threadIdx.x & 31;
    const int grp    = (blockIdx.x * blockDim.x + threadIdx.x) >> 5;
    const int ngrp   = (gridDim.x * blockDim.x) >> 5;

    const float4 w0 = *reinterpret_cast<const float4*>(W + lane32 * 4);
    const float4 w1 = *reinterpret_cast<const float4*>(W + D_FEAT + lane32 * 4);
    const float bb = bias[0];

    // N_NODES % 4 == 0: n0..n0+3 always valid when n0 < N_NODES
    for (int n0 = grp * 4; n0 < N_NODES; n0 += ngrp * 4) {
        float4 f[4];
        #pragma unroll
        for (int j = 0; j < 4; ++j) {
            f[j] = *reinterpret_cast<const float4*>(
                feat + (size_t)(n0 + j) * D_FEAT + lane32 * 4);
        }

        float pa[4], pc[4];
        #pragma unroll
        for (int j = 0; j < 4; ++j) {
            pa[j] = f[j].x * w0.x + f[j].y * w0.y + f[j].z * w0.z + f[j].w * w0.w;
            pc[j] = f[j].x * w1.x + f[j].y * w1.y + f[j].z * w1.z + f[j].w * w1.w;
        }

        #pragma unroll
        for (int off = 16; off > 0; off >>= 1) {
            #pragma unroll
            for (int j = 0; j < 4; ++j) {
                pa[j] += __shfl_down(pa[j], off, 32);
                pc[j] += __shfl_down(pc[j], off, 32);
            }
        }

        if (lane32 == 0) {
            #pragma unroll
            for (int j = 0; j < 4; ++j) {
                a[n0 + j] = pa[j] + bb;   // bias folded here
                c[n0 + j] = pc[j];
            }
        }
    }
}

// ---------------------------------------------------------------------------
// Kernel 2: out[e] = sigmoid(a[src] + c[dst]), 4 edges/thread.
// All 8 gathers issued before the exp chain. Nontemporal output stores keep
// the 800 KB a/c gather tables resident in L2.
// ---------------------------------------------------------------------------
__global__ __launch_bounds__(256) void edge_kernel(
    const int* __restrict__ ei,
    const float* __restrict__ a, const float* __restrict__ c,
    float* __restrict__ out)
{
    const int t = blockIdx.x * blockDim.x + threadIdx.x;
    const int e0 = t * 4;
    if (e0 >= N_EDGES) return;

    const int4 s = *reinterpret_cast<const int4*>(ei + e0);
    const int4 d = *reinterpret_cast<const int4*>(ei + N_EDGES + e0);

    // issue all gathers up front
    const float as0 = a[s.x], as1 = a[s.y], as2 = a[s.z], as3 = a[s.w];
    const float cd0 = c[d.x], cd1 = c[d.y], cd2 = c[d.z], cd3 = c[d.w];

    nfloat4 o;
    o.x = 1.0f / (1.0f + __expf(-(as0 + cd0)));
    o.y = 1.0f / (1.0f + __expf(-(as1 + cd1)));
    o.z = 1.0f / (1.0f + __expf(-(as2 + cd2)));
    o.w = 1.0f / (1.0f + __expf(-(as3 + cd3)));

    __builtin_nontemporal_store(o, reinterpret_cast<nfloat4*>(out + e0));
}

extern "C" void kernel_launch(void* const* d_in, const int* in_sizes, int n_in,
                              void* d_out, int out_size, void* d_ws, size_t ws_size,
                              hipStream_t stream)
{
    const float* feat = (const float*)d_in[0];
    const int*   ei   = (const int*)d_in[1];   // harness converts int64 -> int32
    const float* W    = (const float*)d_in[2];
    const float* b    = (const float*)d_in[3];
    float*       out  = (float*)d_out;

    float* a = (float*)d_ws;
    float* c = a + N_NODES;

    // 2048 blocks = 8/CU even; 16384 groups x 4 nodes in flight
    node_dots_kernel<<<2048, 256, 0, stream>>>(feat, W, b, a, c);

    const int nthreads = N_EDGES / 4;            // 160000
    const int nblk2 = (nthreads + 255) / 256;    // 625
    edge_kernel<<<nblk2, 256, 0, stream>>>(ei, a, c, out);
}